// Round 1
// baseline (82.529 us; speedup 1.0000x reference)
//
#include <hip/hip_runtime.h>
#include <math.h>

#define OUT_H 7
#define OUT_W 7

__global__ void msroi_align_kernel(const float* __restrict__ f0,
                                   const float* __restrict__ f1,
                                   const float* __restrict__ f2,
                                   const float* __restrict__ f3,
                                   const float* __restrict__ boxes,
                                   float* __restrict__ out,
                                   int M, int C, int L, int total)
{
    int idx = blockIdx.x * blockDim.x + threadIdx.x;
    if (idx >= total) return;

    int xw = idx % OUT_W;
    int t  = idx / OUT_W;
    int yh = t % OUT_H;
    t /= OUT_H;
    int c = t % C;
    int m = t / C;
    int b = m / L;

    // box (broadcast across the 49*C threads of this box -> L1/L2 hit)
    float bx1 = boxes[m * 4 + 0];
    float by1 = boxes[m * 4 + 1];
    float bx2 = boxes[m * 4 + 2];
    float by2 = boxes[m * 4 + 3];

    // level selection (match reference fp32 math)
    float sz  = sqrtf((bx2 - bx1 + 1.0f) * (by2 - by1 + 1.0f));
    float lvf = floorf(4.0f + log2f(sz / 224.0f) + 1e-8f);
    lvf = fminf(fmaxf(lvf, 2.0f), 5.0f);
    int lv = (int)lvf - 2;

    const float* feat;
    int H, W;
    float scale;
    switch (lv) {
        case 0:  feat = f0; H = 256; W = 256; scale = 0.25f;    break;
        case 1:  feat = f1; H = 128; W = 128; scale = 0.125f;   break;
        case 2:  feat = f2; H = 64;  W = 64;  scale = 0.0625f;  break;
        default: feat = f3; H = 32;  W = 32;  scale = 0.03125f; break;
    }

    float x1 = bx1 * scale, y1 = by1 * scale;
    float x2 = bx2 * scale, y2 = by2 * scale;
    float roi_w = fmaxf(x2 - x1, 1.0f);
    float roi_h = fmaxf(y2 - y1, 1.0f);
    float bin_w = roi_w * (1.0f / OUT_W);
    float bin_h = roi_h * (1.0f / OUT_H);
    float sx = x1 + ((float)xw + 0.5f) * bin_w;
    float sy = y1 + ((float)yh + 0.5f) * bin_h;

    // _bilinear_axis for x
    bool  vx   = (sx >= -1.0f) && (sx <= (float)W);
    float scx  = fmaxf(sx, 0.0f);
    int   xlr  = (int)floorf(scx);
    bool  hxf  = xlr >= (W - 1);
    int   xl   = hxf ? (W - 1) : xlr;
    int   xh   = hxf ? (W - 1) : (xlr + 1);
    float lx   = hxf ? 0.0f : (scx - (float)xlr);

    // _bilinear_axis for y
    bool  vy   = (sy >= -1.0f) && (sy <= (float)H);
    float scy  = fmaxf(sy, 0.0f);
    int   ylr  = (int)floorf(scy);
    bool  hyf  = ylr >= (H - 1);
    int   yl   = hyf ? (H - 1) : ylr;
    int   yhh  = hyf ? (H - 1) : (ylr + 1);
    float ly   = hyf ? 0.0f : (scy - (float)ylr);

    float val = 0.0f;
    if (vx && vy) {
        size_t base = ((size_t)b * (size_t)C + (size_t)c) * (size_t)(H * W);
        const float* p = feat + base;
        float v00 = p[(size_t)yl  * W + xl];
        float v01 = p[(size_t)yl  * W + xh];
        float v10 = p[(size_t)yhh * W + xl];
        float v11 = p[(size_t)yhh * W + xh];
        float hy = 1.0f - ly, hx = 1.0f - lx;
        val = v00 * (hy * hx) + v01 * (hy * lx) + v10 * (ly * hx) + v11 * (ly * lx);
    }
    out[idx] = val;
}

extern "C" void kernel_launch(void* const* d_in, const int* in_sizes, int n_in,
                              void* d_out, int out_size, void* d_ws, size_t ws_size,
                              hipStream_t stream) {
    const float* f0    = (const float*)d_in[0];
    const float* f1    = (const float*)d_in[1];
    const float* f2    = (const float*)d_in[2];
    const float* f3    = (const float*)d_in[3];
    const float* boxes = (const float*)d_in[4];
    float* out = (float*)d_out;

    const int N = 2;
    const int M = in_sizes[4] / 4;     // total boxes (N*L)
    const int L = M / N;               // boxes per batch
    const int C = 256;
    const int total = M * C * OUT_H * OUT_W;

    int block = 256;
    int grid = (total + block - 1) / block;
    msroi_align_kernel<<<grid, block, 0, stream>>>(f0, f1, f2, f3, boxes, out,
                                                   M, C, L, total);
}